// Round 1
// baseline (2278.318 us; speedup 1.0000x reference)
//
#include <hip/hip_runtime.h>
#include <math.h>

#define DIM_ 1024
#define HEADS_ 16
#define DK_ 64
#define B_ 2
#define L_ 2048
#define BH_ (B_*HEADS_)
#define M_ (B_*L_)

// ---------------------------------------------------------------- QKV GEMM
// C = A @ W + b, written in head-major layout [BH, L, DK].
__global__ __launch_bounds__(256)
void qkv_gemm(const float* __restrict__ xout, const float* __restrict__ xctx,
              const float* __restrict__ Wq, const float* __restrict__ bq,
              const float* __restrict__ Wk, const float* __restrict__ bk,
              const float* __restrict__ Wv, const float* __restrict__ bv,
              float* __restrict__ qh, float* __restrict__ kh, float* __restrict__ vh)
{
    const int which = blockIdx.z;
    const float* __restrict__ A    = (which == 0) ? xout : xctx;
    const float* __restrict__ W    = (which == 0) ? Wq : (which == 1) ? Wk : Wv;
    const float* __restrict__ bias = (which == 0) ? bq : (which == 1) ? bk : bv;
    float* __restrict__ dst        = (which == 0) ? qh : (which == 1) ? kh : vh;

    const int col0 = blockIdx.x * 64;
    const int row0 = blockIdx.y * 64;
    const int tid = threadIdx.x;
    const int tx = tid & 15;
    const int ty = tid >> 4;

    __shared__ float As[64][20];   // 20-float row (80B) keeps float4 stores aligned
    __shared__ float Bs[16][68];

    float acc[4][4] = {{0.f}};

    for (int k0 = 0; k0 < DIM_; k0 += 16) {
        {
            const int r = tid >> 2, c = (tid & 3) * 4;
            const float4 v = *(const float4*)&A[(size_t)(row0 + r) * DIM_ + k0 + c];
            *(float4*)&As[r][c] = v;
        }
        {
            const int r = tid >> 4, c = (tid & 15) * 4;
            const float4 v = *(const float4*)&W[(size_t)(k0 + r) * DIM_ + col0 + c];
            *(float4*)&Bs[r][c] = v;
        }
        __syncthreads();
#pragma unroll
        for (int kk = 0; kk < 16; ++kk) {
            const float a0 = As[ty*4+0][kk];
            const float a1 = As[ty*4+1][kk];
            const float a2 = As[ty*4+2][kk];
            const float a3 = As[ty*4+3][kk];
            const float4 b = *(const float4*)&Bs[kk][tx*4];
            acc[0][0] = fmaf(a0, b.x, acc[0][0]);
            acc[0][1] = fmaf(a0, b.y, acc[0][1]);
            acc[0][2] = fmaf(a0, b.z, acc[0][2]);
            acc[0][3] = fmaf(a0, b.w, acc[0][3]);
            acc[1][0] = fmaf(a1, b.x, acc[1][0]);
            acc[1][1] = fmaf(a1, b.y, acc[1][1]);
            acc[1][2] = fmaf(a1, b.z, acc[1][2]);
            acc[1][3] = fmaf(a1, b.w, acc[1][3]);
            acc[2][0] = fmaf(a2, b.x, acc[2][0]);
            acc[2][1] = fmaf(a2, b.y, acc[2][1]);
            acc[2][2] = fmaf(a2, b.z, acc[2][2]);
            acc[2][3] = fmaf(a2, b.w, acc[2][3]);
            acc[3][0] = fmaf(a3, b.x, acc[3][0]);
            acc[3][1] = fmaf(a3, b.y, acc[3][1]);
            acc[3][2] = fmaf(a3, b.z, acc[3][2]);
            acc[3][3] = fmaf(a3, b.w, acc[3][3]);
        }
        __syncthreads();
    }

    // epilogue: head-major store. col0 is a multiple of 64 so the head is fixed.
    const int h = col0 >> 6;
#pragma unroll
    for (int i = 0; i < 4; ++i) {
        const int row = row0 + ty*4 + i;
        const int b = row >> 11;
        const int l = row & (L_ - 1);
        float4 o;
        o.x = acc[i][0] + bias[col0 + tx*4 + 0];
        o.y = acc[i][1] + bias[col0 + tx*4 + 1];
        o.z = acc[i][2] + bias[col0 + tx*4 + 2];
        o.w = acc[i][3] + bias[col0 + tx*4 + 3];
        *(float4*)&dst[((size_t)((b << 4) + h) * L_ + l) * DK_ + tx*4] = o;
    }
}

// ---------------------------------------------------------------- attention pass 1: row max & sum
__global__ __launch_bounds__(256)
void attn_stats(const float* __restrict__ qh, const float* __restrict__ kh,
                float* __restrict__ rowm, float* __restrict__ rowS)
{
    const int bh  = blockIdx.y;
    const int row = blockIdx.x * 256 + threadIdx.x;

    __shared__ float ks[64][64];

    float4 q4[16];
    const float4* qp = (const float4*)&qh[((size_t)bh * L_ + row) * DK_];
#pragma unroll
    for (int i = 0; i < 16; ++i) q4[i] = qp[i];

    float m = -INFINITY, s = 0.f;

    for (int j0 = 0; j0 < L_; j0 += 64) {
        __syncthreads();
#pragma unroll
        for (int p = 0; p < 4; ++p) {
            const int idx = threadIdx.x + p * 256;
            const int r = idx >> 4, c = (idx & 15) * 4;
            *(float4*)&ks[r][c] = *(const float4*)&kh[((size_t)bh * L_ + j0 + r) * DK_ + c];
        }
        __syncthreads();
        for (int j = 0; j < 64; ++j) {
            float d0 = 0.f, d1 = 0.f, d2 = 0.f, d3 = 0.f;
#pragma unroll
            for (int i = 0; i < 16; ++i) {
                const float4 kv = *(const float4*)&ks[j][i*4];
                d0 = fmaf(q4[i].x, kv.x, d0);
                d1 = fmaf(q4[i].y, kv.y, d1);
                d2 = fmaf(q4[i].z, kv.z, d2);
                d3 = fmaf(q4[i].w, kv.w, d3);
            }
            const float sc = ((d0 + d1) + (d2 + d3)) * 0.125f;
            if (sc > m) { s *= __expf(m - sc); m = sc; }
            s += __expf(sc - m);
        }
    }
    rowm[bh * L_ + row] = m;
    rowS[bh * L_ + row] = s;
}

// ---------------------------------------------------------------- attention pass 2: write attn + ctx^T
__global__ __launch_bounds__(256)
void attn_apply(const float* __restrict__ qh, const float* __restrict__ kh,
                const float* __restrict__ vh,
                const float* __restrict__ rowm, const float* __restrict__ rowS,
                float* __restrict__ attn, float* __restrict__ ctxT)
{
    const int bh  = blockIdx.y;
    const int row = blockIdx.x * 256 + threadIdx.x;

    __shared__ float ks[64][64];
    __shared__ float vs[64][64];

    float4 q4[16];
    const float4* qp = (const float4*)&qh[((size_t)bh * L_ + row) * DK_];
#pragma unroll
    for (int i = 0; i < 16; ++i) q4[i] = qp[i];

    const float m    = rowm[bh * L_ + row];
    const float invs = 1.0f / rowS[bh * L_ + row];

    float4 c4[16];
#pragma unroll
    for (int i = 0; i < 16; ++i) c4[i] = make_float4(0.f, 0.f, 0.f, 0.f);

    float* __restrict__ arow = attn + ((size_t)bh * L_ + row) * L_;

    for (int j0 = 0; j0 < L_; j0 += 64) {
        __syncthreads();
#pragma unroll
        for (int p = 0; p < 4; ++p) {
            const int idx = threadIdx.x + p * 256;
            const int r = idx >> 4, c = (idx & 15) * 4;
            *(float4*)&ks[r][c] = *(const float4*)&kh[((size_t)bh * L_ + j0 + r) * DK_ + c];
            *(float4*)&vs[r][c] = *(const float4*)&vh[((size_t)bh * L_ + j0 + r) * DK_ + c];
        }
        __syncthreads();
        for (int jq = 0; jq < 16; ++jq) {
            float a[4];
#pragma unroll
            for (int u = 0; u < 4; ++u) {
                const int j = jq*4 + u;
                float d0 = 0.f, d1 = 0.f, d2 = 0.f, d3 = 0.f;
#pragma unroll
                for (int i = 0; i < 16; ++i) {
                    const float4 kv = *(const float4*)&ks[j][i*4];
                    d0 = fmaf(q4[i].x, kv.x, d0);
                    d1 = fmaf(q4[i].y, kv.y, d1);
                    d2 = fmaf(q4[i].z, kv.z, d2);
                    d3 = fmaf(q4[i].w, kv.w, d3);
                }
                const float sc = ((d0 + d1) + (d2 + d3)) * 0.125f;
                a[u] = __expf(sc - m) * invs;
#pragma unroll
                for (int i = 0; i < 16; ++i) {
                    const float4 vv = *(const float4*)&vs[j][i*4];
                    c4[i].x = fmaf(a[u], vv.x, c4[i].x);
                    c4[i].y = fmaf(a[u], vv.y, c4[i].y);
                    c4[i].z = fmaf(a[u], vv.z, c4[i].z);
                    c4[i].w = fmaf(a[u], vv.w, c4[i].w);
                }
            }
            float4 a4 = make_float4(a[0], a[1], a[2], a[3]);
            *(float4*)&arow[j0 + jq*4] = a4;
        }
    }

    // ctx^T store: ctxT[bh][d][row], coalesced across threads (thread == row)
#pragma unroll
    for (int i = 0; i < 16; ++i) {
        ctxT[((size_t)bh * DK_ + i*4 + 0) * L_ + row] = c4[i].x;
        ctxT[((size_t)bh * DK_ + i*4 + 1) * L_ + row] = c4[i].y;
        ctxT[((size_t)bh * DK_ + i*4 + 2) * L_ + row] = c4[i].z;
        ctxT[((size_t)bh * DK_ + i*4 + 3) * L_ + row] = c4[i].w;
    }
}

// ---------------------------------------------------------------- output projection
// out[rr, n] = tanh( sum_{m<1024} concat[rr,m]*Wo[m,n] + sum_j output[rr,j]*Wo[1024+j,n] + bo[n] )
// concat row (b,l) = ctxT[b*16 + (l>>7)][(l&127)>>1][(l&1)*1024 ... +1024)   (contiguous)
__global__ __launch_bounds__(256)
void out_gemm(const float* __restrict__ ctxT, const float* __restrict__ xout,
              const float* __restrict__ Wo, const float* __restrict__ bo,
              float* __restrict__ out)
{
    const int col0 = blockIdx.x * 64;
    const int row0 = blockIdx.y * 64;
    const int tid = threadIdx.x;
    const int tx = tid & 15;
    const int ty = tid >> 4;

    __shared__ float As[64][20];
    __shared__ float Bs[16][68];
    __shared__ int rowoff[64];

    if (tid < 64) {
        const int rr = row0 + tid;
        const int b = rr >> 11;
        const int l = rr & (L_ - 1);
        const int bh = (b << 4) + (l >> 7);
        const int d = (l & 127) >> 1;
        rowoff[tid] = ((bh * DK_ + d) << 11) + ((l & 1) << 10);
    }
    __syncthreads();

    const int ra = tid >> 2;             // A-load row (0..63)
    const int ca = (tid & 3) * 4;        // A-load k offset
    const int off1 = rowoff[ra];
    const float* __restrict__ p2 = xout + (size_t)(row0 + ra) * DIM_ + ca;

    float acc[4][4] = {{0.f}};

    for (int k0 = 0; k0 < 2 * DIM_; k0 += 16) {
        {
            const float4 v = (k0 < DIM_)
                ? *(const float4*)&ctxT[off1 + k0 + ca]
                : *(const float4*)&p2[k0 - DIM_];
            *(float4*)&As[ra][ca] = v;
        }
        {
            const int r = tid >> 4, c = (tid & 15) * 4;
            const float4 v = *(const float4*)&Wo[(size_t)(k0 + r) * DIM_ + col0 + c];
            *(float4*)&Bs[r][c] = v;
        }
        __syncthreads();
#pragma unroll
        for (int kk = 0; kk < 16; ++kk) {
            const float a0 = As[ty*4+0][kk];
            const float a1 = As[ty*4+1][kk];
            const float a2 = As[ty*4+2][kk];
            const float a3 = As[ty*4+3][kk];
            const float4 b = *(const float4*)&Bs[kk][tx*4];
            acc[0][0] = fmaf(a0, b.x, acc[0][0]);
            acc[0][1] = fmaf(a0, b.y, acc[0][1]);
            acc[0][2] = fmaf(a0, b.z, acc[0][2]);
            acc[0][3] = fmaf(a0, b.w, acc[0][3]);
            acc[1][0] = fmaf(a1, b.x, acc[1][0]);
            acc[1][1] = fmaf(a1, b.y, acc[1][1]);
            acc[1][2] = fmaf(a1, b.z, acc[1][2]);
            acc[1][3] = fmaf(a1, b.w, acc[1][3]);
            acc[2][0] = fmaf(a2, b.x, acc[2][0]);
            acc[2][1] = fmaf(a2, b.y, acc[2][1]);
            acc[2][2] = fmaf(a2, b.z, acc[2][2]);
            acc[2][3] = fmaf(a2, b.w, acc[2][3]);
            acc[3][0] = fmaf(a3, b.x, acc[3][0]);
            acc[3][1] = fmaf(a3, b.y, acc[3][1]);
            acc[3][2] = fmaf(a3, b.z, acc[3][2]);
            acc[3][3] = fmaf(a3, b.w, acc[3][3]);
        }
        __syncthreads();
    }

#pragma unroll
    for (int i = 0; i < 4; ++i) {
        const int rr = row0 + ty*4 + i;
        float4 o;
        o.x = tanhf(acc[i][0] + bo[col0 + tx*4 + 0]);
        o.y = tanhf(acc[i][1] + bo[col0 + tx*4 + 1]);
        o.z = tanhf(acc[i][2] + bo[col0 + tx*4 + 2]);
        o.w = tanhf(acc[i][3] + bo[col0 + tx*4 + 3]);
        *(float4*)&out[(size_t)rr * DIM_ + col0 + tx*4] = o;
    }
}

// ---------------------------------------------------------------- launch
extern "C" void kernel_launch(void* const* d_in, const int* in_sizes, int n_in,
                              void* d_out, int out_size, void* d_ws, size_t ws_size,
                              hipStream_t stream)
{
    const float* xout = (const float*)d_in[0];
    const float* xctx = (const float*)d_in[1];
    const float* Wq = (const float*)d_in[2];
    const float* bq = (const float*)d_in[3];
    const float* Wk = (const float*)d_in[4];
    const float* bk = (const float*)d_in[5];
    const float* Wv = (const float*)d_in[6];
    const float* bv = (const float*)d_in[7];
    const float* Wo = (const float*)d_in[8];
    const float* bo = (const float*)d_in[9];

    float* out  = (float*)d_out;                       // [B, L, DIM]
    float* attn = out + (size_t)B_ * L_ * DIM_;        // [BH, L, L]

    float* ws   = (float*)d_ws;
    float* qh   = ws;                                  // [BH, L, DK]
    float* kh   = qh + (size_t)BH_ * L_ * DK_;
    float* vh   = kh + (size_t)BH_ * L_ * DK_;
    float* ctxT = vh + (size_t)BH_ * L_ * DK_;         // [BH, DK, L]
    float* rowm = ctxT + (size_t)BH_ * DK_ * L_;       // [BH*L]
    float* rowS = rowm + (size_t)BH_ * L_;             // [BH*L]

    {
        dim3 grid(DIM_ / 64, M_ / 64, 3);
        qkv_gemm<<<grid, 256, 0, stream>>>(xout, xctx, Wq, bq, Wk, bk, Wv, bv, qh, kh, vh);
    }
    {
        dim3 grid(L_ / 256, BH_);
        attn_stats<<<grid, 256, 0, stream>>>(qh, kh, rowm, rowS);
        attn_apply<<<grid, 256, 0, stream>>>(qh, kh, vh, rowm, rowS, attn, ctxT);
    }
    {
        dim3 grid(DIM_ / 64, M_ / 64);
        out_gemm<<<grid, 256, 0, stream>>>(ctxT, xout, Wo, bo, out);
    }
}

// Round 2
// 459.394 us; speedup vs baseline: 4.9594x; 4.9594x over previous
//
#include <hip/hip_runtime.h>
#include <math.h>
#include <stdint.h>

#define DIM_ 1024
#define HEADS_ 16
#define DK_ 64
#define B_ 2
#define L_ 2048
#define BH_ (B_*HEADS_)
#define M_ (B_*L_)

typedef __attribute__((ext_vector_type(4))) float f32x4;
typedef __attribute__((ext_vector_type(8))) short bf16x8;
typedef __attribute__((ext_vector_type(4))) short bf16x4;

static __device__ __forceinline__ short f2bf(float f) {
    uint32_t u = __builtin_bit_cast(uint32_t, f);
    u += 0x7fffu + ((u >> 16) & 1u);          // round-to-nearest-even
    return (short)(u >> 16);
}

// ------------------------------------------------------------ prep: fp32 -> bf16
__global__ __launch_bounds__(256)
void cvt_bf16(const float* __restrict__ a, const float* __restrict__ b,
              short* __restrict__ ao, short* __restrict__ bo)
{
    const int id = blockIdx.x * 256 + threadIdx.x;    // one 8-elem chunk
    const int nA = (M_ * DIM_) / 8;
    const float* src = (id < nA) ? a : b;
    short* dst = (id < nA) ? ao : bo;
    const int c = (id < nA) ? id : id - nA;
    const f32x4 v0 = *(const f32x4*)&src[(size_t)c * 8];
    const f32x4 v1 = *(const f32x4*)&src[(size_t)c * 8 + 4];
    bf16x8 o;
#pragma unroll
    for (int i = 0; i < 4; ++i) { o[i] = f2bf(v0[i]); o[4 + i] = f2bf(v1[i]); }
    *(bf16x8*)&dst[(size_t)c * 8] = o;
}

// ------------------------------------------------------------ prep: W[k][n] -> WT[n][k] bf16
__global__ __launch_bounds__(256)
void wtrans(const float* __restrict__ Wq, const float* __restrict__ Wk,
            const float* __restrict__ Wv, const float* __restrict__ Wo,
            short* __restrict__ WqT, short* __restrict__ WkT,
            short* __restrict__ WvT, short* __restrict__ WoT)
{
    const int z = blockIdx.z;
    const int K = (z == 3) ? 2 * DIM_ : DIM_;
    const int k0 = blockIdx.x * 64;
    if (k0 >= K) return;
    const int n0 = blockIdx.y * 64;
    const float* W = (z == 0) ? Wq : (z == 1) ? Wk : (z == 2) ? Wv : Wo;
    short* WT = (z == 0) ? WqT : (z == 1) ? WkT : (z == 2) ? WvT : WoT;

    __shared__ float ts[64][65];
    const int tid = threadIdx.x;
    {
        const int k = tid >> 2, noff = (tid & 3) * 16;
#pragma unroll
        for (int i = 0; i < 4; ++i)
            *(f32x4*)&ts[k][noff + i * 4] =
                *(const f32x4*)&W[(size_t)(k0 + k) * DIM_ + n0 + noff + i * 4];
    }
    __syncthreads();
    {
        const int n = tid >> 2, koff = (tid & 3) * 16;
#pragma unroll
        for (int c = 0; c < 2; ++c) {
            bf16x8 o;
#pragma unroll
            for (int i = 0; i < 8; ++i) o[i] = f2bf(ts[koff + c * 8 + i][n]);
            *(bf16x8*)&WT[(size_t)(n0 + n) * K + k0 + koff + c * 8] = o;
        }
    }
}

// ------------------------------------------------------------ QKV GEMM (MFMA)
// A: xb [4096][1024] bf16 row-major; B: WT [1024][1024] bf16 [n][k].
// q -> qh [BH][L][DK] (scaled 1/8), k -> kh [BH][L][DK], v -> vT [BH][DK][L].
__global__ __launch_bounds__(256)
void qkv_mfma(const short* __restrict__ xoutb, const short* __restrict__ xctxb,
              const short* __restrict__ WqT, const short* __restrict__ WkT,
              const short* __restrict__ WvT,
              const float* __restrict__ bq, const float* __restrict__ bk,
              const float* __restrict__ bv,
              short* __restrict__ qh, short* __restrict__ kh, short* __restrict__ vT)
{
    const int z = blockIdx.z;
    const short* A  = (z == 0) ? xoutb : xctxb;
    const short* Bt = (z == 0) ? WqT : (z == 1) ? WkT : WvT;
    const float* bias = (z == 0) ? bq : (z == 1) ? bk : bv;

    const int col0 = blockIdx.x * 128;
    const int row0 = blockIdx.y * 128;
    const int tid = threadIdx.x;
    const int lane = tid & 63;
    const int w = tid >> 6;
    const int wm = (w >> 1) * 64, wn = (w & 1) * 64;
    const int l15 = lane & 15, lk = (lane >> 4) * 8;

    __shared__ short As[128][56];   // 112B stride: 16B-aligned, 2-way max conflict
    __shared__ short Bs[128][56];

    f32x4 acc[4][4];
#pragma unroll
    for (int mi = 0; mi < 4; ++mi)
#pragma unroll
        for (int ni = 0; ni < 4; ++ni) acc[mi][ni] = (f32x4)0.f;

    for (int k0 = 0; k0 < DIM_; k0 += 32) {
        __syncthreads();
#pragma unroll
        for (int p = 0; p < 2; ++p) {
            const int c = tid + p * 256;
            const int r = c >> 2, koff = (c & 3) * 8;
            *(bf16x8*)&As[r][koff] = *(const bf16x8*)&A[(size_t)(row0 + r) * DIM_ + k0 + koff];
            *(bf16x8*)&Bs[r][koff] = *(const bf16x8*)&Bt[(size_t)(col0 + r) * DIM_ + k0 + koff];
        }
        __syncthreads();
        bf16x8 af[4], bfr[4];
#pragma unroll
        for (int mi = 0; mi < 4; ++mi) af[mi] = *(const bf16x8*)&As[wm + mi * 16 + l15][lk];
#pragma unroll
        for (int ni = 0; ni < 4; ++ni) bfr[ni] = *(const bf16x8*)&Bs[wn + ni * 16 + l15][lk];
#pragma unroll
        for (int mi = 0; mi < 4; ++mi)
#pragma unroll
            for (int ni = 0; ni < 4; ++ni)
                acc[mi][ni] = __builtin_amdgcn_mfma_f32_16x16x32_bf16(af[mi], bfr[ni], acc[mi][ni], 0, 0, 0);
    }

#pragma unroll
    for (int ni = 0; ni < 4; ++ni) {
        const int col = col0 + wn + ni * 16 + l15;
        const int h = col >> 6, dk = col & 63;
        const float bb = bias[col];
#pragma unroll
        for (int mi = 0; mi < 4; ++mi) {
            const int rowb = row0 + wm + mi * 16 + (lane >> 4) * 4;
            const int b = rowb >> 11;
            const int l = rowb & (L_ - 1);
            const int bh = b * 16 + h;
            if (z == 2) {
                bf16x4 o;
#pragma unroll
                for (int r = 0; r < 4; ++r) o[r] = f2bf(acc[mi][ni][r] + bb);
                *(bf16x4*)&vT[(size_t)(bh * 64 + dk) * L_ + l] = o;
            } else {
                short* dst = (z == 0) ? qh : kh;
                const float sc = (z == 0) ? 0.125f : 1.0f;
#pragma unroll
                for (int r = 0; r < 4; ++r)
                    dst[((size_t)bh * L_ + l + r) * DK_ + dk] = f2bf((acc[mi][ni][r] + bb) * sc);
            }
        }
    }
}

// ------------------------------------------------------------ fused attention (MFMA, 2-pass)
__global__ __launch_bounds__(256)
void attn_mfma(const short* __restrict__ qh, const short* __restrict__ kh,
               const short* __restrict__ vT,
               float* __restrict__ attn, short* __restrict__ ctxTb)
{
    const int bh = blockIdx.y;
    const int q0 = blockIdx.x * 64;
    const int tid = threadIdx.x;
    const int lane = tid & 63;
    const int w = tid >> 6;
    const int l15 = lane & 15, g = lane >> 4;
    const int lk = g * 8;

    __shared__ short Ks[64][72];   // [kv][dk]
    __shared__ short Vs[64][72];   // [dk][kv]
    __shared__ float Ps[64][68];   // [q][kv] fp32

    bf16x8 qf[2];
#pragma unroll
    for (int ks = 0; ks < 2; ++ks)
        qf[ks] = *(const bf16x8*)&qh[((size_t)bh * L_ + q0 + w * 16 + l15) * DK_ + ks * 32 + lk];

    float m_run[4], s_run[4];
#pragma unroll
    for (int r = 0; r < 4; ++r) { m_run[r] = -1e30f; s_run[r] = 0.f; }

    // ---- pass 1: online stats
    for (int j0 = 0; j0 < L_; j0 += 64) {
        __syncthreads();
#pragma unroll
        for (int p = 0; p < 2; ++p) {
            const int c = tid + p * 256;
            const int r = c >> 3, doff = (c & 7) * 8;
            *(bf16x8*)&Ks[r][doff] = *(const bf16x8*)&kh[((size_t)bh * L_ + j0 + r) * DK_ + doff];
        }
        __syncthreads();
        f32x4 sa[4];
#pragma unroll
        for (int c = 0; c < 4; ++c) sa[c] = (f32x4)0.f;
#pragma unroll
        for (int c = 0; c < 4; ++c)
#pragma unroll
            for (int ks = 0; ks < 2; ++ks) {
                const bf16x8 kb = *(const bf16x8*)&Ks[c * 16 + l15][ks * 32 + lk];
                sa[c] = __builtin_amdgcn_mfma_f32_16x16x32_bf16(qf[ks], kb, sa[c], 0, 0, 0);
            }
#pragma unroll
        for (int r = 0; r < 4; ++r) {
            float tm = fmaxf(fmaxf(sa[0][r], sa[1][r]), fmaxf(sa[2][r], sa[3][r]));
            tm = fmaxf(tm, __shfl_xor(tm, 1));
            tm = fmaxf(tm, __shfl_xor(tm, 2));
            tm = fmaxf(tm, __shfl_xor(tm, 4));
            tm = fmaxf(tm, __shfl_xor(tm, 8));
            const float mn = fmaxf(m_run[r], tm);
            float ts = __expf(sa[0][r] - mn) + __expf(sa[1][r] - mn)
                     + __expf(sa[2][r] - mn) + __expf(sa[3][r] - mn);
            ts += __shfl_xor(ts, 1); ts += __shfl_xor(ts, 2);
            ts += __shfl_xor(ts, 4); ts += __shfl_xor(ts, 8);
            s_run[r] = s_run[r] * __expf(m_run[r] - mn) + ts;
            m_run[r] = mn;
        }
    }
    float inv_s[4];
#pragma unroll
    for (int r = 0; r < 4; ++r) inv_s[r] = 1.0f / s_run[r];

    f32x4 cacc[4];
#pragma unroll
    for (int nf = 0; nf < 4; ++nf) cacc[nf] = (f32x4)0.f;

    // ---- pass 2: recompute S, write attn, accumulate PV
    for (int j0 = 0; j0 < L_; j0 += 64) {
        __syncthreads();
#pragma unroll
        for (int p = 0; p < 2; ++p) {
            const int c = tid + p * 256;
            const int r = c >> 3, doff = (c & 7) * 8;
            *(bf16x8*)&Ks[r][doff] = *(const bf16x8*)&kh[((size_t)bh * L_ + j0 + r) * DK_ + doff];
            *(bf16x8*)&Vs[r][doff] = *(const bf16x8*)&vT[(size_t)(bh * 64 + r) * L_ + j0 + doff];
        }
        __syncthreads();
        f32x4 sa[4];
#pragma unroll
        for (int c = 0; c < 4; ++c) sa[c] = (f32x4)0.f;
#pragma unroll
        for (int c = 0; c < 4; ++c)
#pragma unroll
            for (int ks = 0; ks < 2; ++ks) {
                const bf16x8 kb = *(const bf16x8*)&Ks[c * 16 + l15][ks * 32 + lk];
                sa[c] = __builtin_amdgcn_mfma_f32_16x16x32_bf16(qf[ks], kb, sa[c], 0, 0, 0);
            }
#pragma unroll
        for (int c = 0; c < 4; ++c)
#pragma unroll
            for (int r = 0; r < 4; ++r)
                Ps[w * 16 + g * 4 + r][c * 16 + l15] = __expf(sa[c][r] - m_run[r]) * inv_s[r];
        __syncthreads();
        // coalesced attn write: each 4 threads cover a 256B row segment
        {
            const int row = tid >> 2, coff = (tid & 3) * 16;
            float* dst = &attn[((size_t)bh * L_ + q0 + row) * L_ + j0 + coff];
#pragma unroll
            for (int i = 0; i < 4; ++i)
                *(f32x4*)&dst[i * 4] = *(const f32x4*)&Ps[row][coff + i * 4];
        }
        // PV
        bf16x8 pa[2];
#pragma unroll
        for (int ks = 0; ks < 2; ++ks) {
            const f32x4 p0 = *(const f32x4*)&Ps[w * 16 + l15][ks * 32 + lk];
            const f32x4 p1 = *(const f32x4*)&Ps[w * 16 + l15][ks * 32 + lk + 4];
            bf16x8 t;
#pragma unroll
            for (int i = 0; i < 4; ++i) { t[i] = f2bf(p0[i]); t[4 + i] = f2bf(p1[i]); }
            pa[ks] = t;
        }
#pragma unroll
        for (int nf = 0; nf < 4; ++nf)
#pragma unroll
            for (int ks = 0; ks < 2; ++ks) {
                const bf16x8 vb = *(const bf16x8*)&Vs[nf * 16 + l15][ks * 32 + lk];
                cacc[nf] = __builtin_amdgcn_mfma_f32_16x16x32_bf16(pa[ks], vb, cacc[nf], 0, 0, 0);
            }
    }

    // ctx^T epilogue (bf16, [BH][DK][L])
#pragma unroll
    for (int nf = 0; nf < 4; ++nf) {
        const int dk = nf * 16 + l15;
        const int q = q0 + w * 16 + g * 4;
        bf16x4 o;
#pragma unroll
        for (int r = 0; r < 4; ++r) o[r] = f2bf(cacc[nf][r]);
        *(bf16x4*)&ctxTb[(size_t)(bh * 64 + dk) * L_ + q] = o;
    }
}

// ------------------------------------------------------------ output projection (MFMA)
__global__ __launch_bounds__(256)
void out_mfma(const short* __restrict__ ctxTb, const short* __restrict__ xoutb,
              const short* __restrict__ WoT, const float* __restrict__ bo,
              float* __restrict__ out)
{
    const int col0 = blockIdx.x * 128;
    const int row0 = blockIdx.y * 128;
    const int tid = threadIdx.x;
    const int lane = tid & 63;
    const int w = tid >> 6;
    const int wm = (w >> 1) * 64, wn = (w & 1) * 64;
    const int l15 = lane & 15, lk = (lane >> 4) * 8;

    __shared__ short As[128][56];
    __shared__ short Bs[128][56];
    __shared__ int rowoff[128];

    if (tid < 128) {
        const int rr = row0 + tid;
        const int b = rr >> 11;
        const int l = rr & (L_ - 1);
        const int bh = b * 16 + (l >> 7);
        const int d = (l & 127) >> 1;
        rowoff[tid] = ((bh * 64 + d) << 11) + ((l & 1) << 10);
    }
    __syncthreads();

    f32x4 acc[4][4];
#pragma unroll
    for (int mi = 0; mi < 4; ++mi)
#pragma unroll
        for (int ni = 0; ni < 4; ++ni) acc[mi][ni] = (f32x4)0.f;

    for (int k0 = 0; k0 < 2 * DIM_; k0 += 32) {
        __syncthreads();
#pragma unroll
        for (int p = 0; p < 2; ++p) {
            const int c = tid + p * 256;
            const int r = c >> 2, koff = (c & 3) * 8;
            const int k = k0 + koff;
            const short* src = (k < DIM_) ? &ctxTb[rowoff[r] + k]
                                          : &xoutb[(size_t)(row0 + r) * DIM_ + (k - DIM_)];
            *(bf16x8*)&As[r][koff] = *(const bf16x8*)src;
            *(bf16x8*)&Bs[r][koff] = *(const bf16x8*)&WoT[(size_t)(col0 + r) * (2 * DIM_) + k];
        }
        __syncthreads();
        bf16x8 af[4], bfr[4];
#pragma unroll
        for (int mi = 0; mi < 4; ++mi) af[mi] = *(const bf16x8*)&As[wm + mi * 16 + l15][lk];
#pragma unroll
        for (int ni = 0; ni < 4; ++ni) bfr[ni] = *(const bf16x8*)&Bs[wn + ni * 16 + l15][lk];
#pragma unroll
        for (int mi = 0; mi < 4; ++mi)
#pragma unroll
            for (int ni = 0; ni < 4; ++ni)
                acc[mi][ni] = __builtin_amdgcn_mfma_f32_16x16x32_bf16(af[mi], bfr[ni], acc[mi][ni], 0, 0, 0);
    }

#pragma unroll
    for (int ni = 0; ni < 4; ++ni) {
        const int col = col0 + wn + ni * 16 + l15;
        const float bb = bo[col];
#pragma unroll
        for (int mi = 0; mi < 4; ++mi) {
            const int rowb = row0 + wm + mi * 16 + (lane >> 4) * 4;
#pragma unroll
            for (int r = 0; r < 4; ++r)
                out[(size_t)(rowb + r) * DIM_ + col] = tanhf(acc[mi][ni][r] + bb);
        }
    }
}

// ------------------------------------------------------------ launch
extern "C" void kernel_launch(void* const* d_in, const int* in_sizes, int n_in,
                              void* d_out, int out_size, void* d_ws, size_t ws_size,
                              hipStream_t stream)
{
    const float* xout = (const float*)d_in[0];
    const float* xctx = (const float*)d_in[1];
    const float* Wq = (const float*)d_in[2];
    const float* bq = (const float*)d_in[3];
    const float* Wk = (const float*)d_in[4];
    const float* bk = (const float*)d_in[5];
    const float* Wv = (const float*)d_in[6];
    const float* bv = (const float*)d_in[7];
    const float* Wo = (const float*)d_in[8];
    const float* bo = (const float*)d_in[9];

    float* out  = (float*)d_out;
    float* attn = out + (size_t)M_ * DIM_;

    short* ws = (short*)d_ws;
    short* xoutb = ws;                                   // 4M
    short* xctxb = xoutb + (size_t)M_ * DIM_;            // 4M
    short* WqT   = xctxb + (size_t)M_ * DIM_;            // 1M
    short* WkT   = WqT + (size_t)DIM_ * DIM_;
    short* WvT   = WkT + (size_t)DIM_ * DIM_;
    short* WoT   = WvT + (size_t)DIM_ * DIM_;            // 2M
    short* qh    = WoT + (size_t)2 * DIM_ * DIM_;        // 4M
    short* kh    = qh + (size_t)BH_ * L_ * DK_;
    short* vT    = kh + (size_t)BH_ * L_ * DK_;
    short* ctxTb = vT + (size_t)BH_ * L_ * DK_;          // 4M

    cvt_bf16<<<(2 * M_ * DIM_ / 8) / 256, 256, 0, stream>>>(xout, xctx, xoutb, xctxb);
    wtrans<<<dim3(32, 16, 4), 256, 0, stream>>>(Wq, Wk, Wv, Wo, WqT, WkT, WvT, WoT);
    qkv_mfma<<<dim3(DIM_ / 128, M_ / 128, 3), 256, 0, stream>>>(
        xoutb, xctxb, WqT, WkT, WvT, bq, bk, bv, qh, kh, vT);
    attn_mfma<<<dim3(L_ / 64, BH_), 256, 0, stream>>>(qh, kh, vT, attn, ctxTb);
    out_mfma<<<dim3(DIM_ / 128, M_ / 128), 256, 0, stream>>>(ctxTb, xoutb, WoT, bo, out);
}